// Round 10
// baseline (433.626 us; speedup 1.0000x reference)
//
#include <hip/hip_runtime.h>
#include <hip/hip_bf16.h>
#include <hip/hip_cooperative_groups.h>
#include <stdint.h>

namespace cg = cooperative_groups;

// LightNet attention fwd. B=2, T=2048, HID=1024, H=8, DK=DV=128, LR=128.
// Contract (R1-R4): inputs fp32, output fp32.
//
// o_t[v] = scale * sum_k (q_t[k]/E_t[k]) * sum_{s<=t} e_s[k] v_s[v],
// e=exp(k), E=cumsum(e). Chunked Tc=128.
// R10: pass1+pass2+pass3+norm fused into ONE cooperative kernel (256 blocks
// = 1/CU, grid.sync at the 3 cross-block deps). O stays in LDS end-to-end:
// Oatt global round-trip (16MB) eliminated; 8 -> 5 launches.
// GEMMs: bf16 MFMA 128x128 tile, BK=64 (2x32 sub-tiles per barrier pair),
// global_load_lds width-16 staging, LDS-staged coalesced bf16 epilogue.

typedef short short8 __attribute__((ext_vector_type(8)));
typedef float f32x4 __attribute__((ext_vector_type(4)));

#define T_SEQ 2048
#define HIDN  1024
#define SCALE 0.08838834764831845f   // 128^-0.5
#define LDSP  136                    // padded LDS row stride (shorts)

// ---------------- bf16 bit helpers ----------------
__device__ __forceinline__ float blo(unsigned int u){
  union{unsigned int i; float f;} v; v.i = u << 16; return v.f;
}
__device__ __forceinline__ float bhi(unsigned int u){
  union{unsigned int i; float f;} v; v.i = u & 0xffff0000u; return v.f;
}
__device__ __forceinline__ float bu2f(unsigned short u){
  union{unsigned int i; float f;} v; v.i = ((unsigned int)u) << 16; return v.f;
}
__device__ __forceinline__ unsigned short f2bu(float f){
  union{float f; unsigned int i;} v; v.f = f;
  unsigned int x = v.i;
  x += 0x7fffu + ((x >> 16) & 1u);     // RNE
  return (unsigned short)(x >> 16);
}
__device__ __forceinline__ void up8(const unsigned short* p, float* f){
  uint4 v = *(const uint4*)p;
  f[0]=blo(v.x); f[1]=bhi(v.x); f[2]=blo(v.y); f[3]=bhi(v.y);
  f[4]=blo(v.z); f[5]=bhi(v.z); f[6]=blo(v.w); f[7]=bhi(v.w);
}
__device__ __forceinline__ void async16(const void* g, void* l){
  __builtin_amdgcn_global_load_lds(
      (const __attribute__((address_space(1))) unsigned int*)g,
      (__attribute__((address_space(3))) unsigned int*)l, 16, 0, 0);
}

// ---------------- fused input cast + SumSq zeroing ------------------------
__global__ __launch_bounds__(256) void convert_all(
    const float* __restrict__ X,  const float* __restrict__ Wq,
    const float* __restrict__ Wk, const float* __restrict__ Wv,
    const float* __restrict__ Wg1,const float* __restrict__ Wg2,
    const float* __restrict__ gnw,const float* __restrict__ Wo,
    unsigned short* __restrict__ base, float* __restrict__ SumSq)
{
  int q = blockIdx.x * 256 + threadIdx.x;
  const float* src; unsigned short* dst; int rel = q;
  if (rel < 1048576)            { src = X;   dst = base;            }
  else if ((rel -= 1048576) < 262144) { src = Wq;  dst = base + 4194304; }
  else if ((rel -=  262144) < 262144) { src = Wk;  dst = base + 5242880; }
  else if ((rel -=  262144) < 262144) { src = Wv;  dst = base + 6291456; }
  else if ((rel -=  262144) < 262144) { src = Wo;  dst = base + 7340032; }
  else if ((rel -=  262144) <  32768) { src = Wg1; dst = base + 8388608; }
  else if ((rel -=   32768) <  32768) { src = Wg2; dst = base + 8519680; }
  else if ((rel -=   32768) <    256) { src = gnw; dst = base + 8650752; }
  else { rel -= 256;                              // zero SumSq (4096 floats)
    ((float4*)SumSq)[rel] = make_float4(0.f,0.f,0.f,0.f); return; }
  float4 v = ((const float4*)src)[rel];
  ushort4 o; o.x=f2bu(v.x); o.y=f2bu(v.y); o.z=f2bu(v.z); o.w=f2bu(v.w);
  ((ushort4*)dst)[rel] = o;
}

// ---------------- MFMA GEMM core: C(128x128)=A@B^T, BK=64 (2x32) ---------
__device__ __forceinline__ void gemm_core(
    const unsigned short* __restrict__ A, const unsigned short* __restrict__ B,
    int K, int row0, int col0,
    unsigned short* sA, unsigned short* sB, f32x4 acc[4][4], int tid)
{
  const int lane = tid & 63;
  const int wm = (tid >> 6) & 1, wn = tid >> 7;
  const int wb = tid & 192;                // wave-uniform chunk base
  for (int k0 = 0; k0 < K; k0 += 64){
    __syncthreads();                       // prev iter's LDS reads done
#pragma unroll
    for (int h = 0; h < 2; ++h){
#pragma unroll
      for (int r = 0; r < 2; ++r){
        int idx  = r*256 + tid;            // 512 chunks of 16B per sub-tile
        int mrow = idx >> 2, kc = (idx & 3) * 8;
        async16(A + (size_t)(row0 + mrow)*K + k0 + h*32 + kc,
                sA + (size_t)(h*512 + r*256 + wb)*8);
        async16(B + (size_t)(col0 + mrow)*K + k0 + h*32 + kc,
                sB + (size_t)(h*512 + r*256 + wb)*8);
      }
    }
    __syncthreads();                       // drains vmcnt before barrier
#pragma unroll
    for (int h = 0; h < 2; ++h){
      short8 av[4], bv[4];
#pragma unroll
      for (int i=0;i<4;i++)
        av[i] = *(const short8*)(sA + h*4096 + (size_t)(wm*64 + i*16 + (lane&15))*32 + (lane>>4)*8);
#pragma unroll
      for (int j=0;j<4;j++)
        bv[j] = *(const short8*)(sB + h*4096 + (size_t)(wn*64 + j*16 + (lane&15))*32 + (lane>>4)*8);
#pragma unroll
      for (int i=0;i<4;i++)
#pragma unroll
        for (int j=0;j<4;j++)
          acc[i][j] = __builtin_amdgcn_mfma_f32_16x16x32_bf16(av[i], bv[j], acc[i][j], 0, 0, 0);
    }
  }
}

// bf16 epilogue via LDS. act: 0 none, 1 silu/swish, 2 exp.
__device__ __forceinline__ void epilogue_lds(
    f32x4 acc[4][4], int row0, int col0, int tid, int ldc, int act,
    unsigned short* __restrict__ Cb, unsigned short* sC)
{
  const int lane = tid & 63;
  const int wm = (tid >> 6) & 1, wn = tid >> 7;
#pragma unroll
  for (int p=0;p<4;p++){
    __syncthreads();
    if (wm == (p>>1)){
#pragma unroll
      for (int ii=0; ii<2; ii++){
        int i = (p&1)*2 + ii;
        int lr = i*16 + ((lane>>4)<<2) - (p&1)*32;   // local row in [0,32)
#pragma unroll
        for (int j=0;j<4;j++){
          int col = wn*64 + j*16 + (lane&15);
#pragma unroll
          for (int r=0;r<4;r++){
            float v = acc[i][j][r];
            if (act == 1) v = v / (1.f + __expf(-v));
            else if (act == 2) v = __expf(v);
            sC[(lr+r)*128 + col] = f2bu(v);
          }
        }
      }
    }
    __syncthreads();
#pragma unroll
    for (int c = tid; c < 512; c += 256){  // 32 rows x 256B
      int rr = c >> 4, off = (c & 15)*8;
      *(uint4*)&Cb[(size_t)(row0 + p*32 + rr)*ldc + col0 + off] =
          *(const uint4*)&sC[rr*128 + off];
    }
  }
}

// fp32 direct epilogue (64B full-line segments).
__device__ __forceinline__ void epilogue_f32(
    f32x4 acc[4][4], int row0, int col0, int tid, int ldc,
    float* __restrict__ Cf)
{
  const int lane = tid & 63;
  const int wm = (tid >> 6) & 1, wn = tid >> 7;
#pragma unroll
  for (int i=0;i<4;i++){
    int rbase = row0 + wm*64 + i*16 + ((lane>>4)<<2);
#pragma unroll
    for (int j=0;j<4;j++){
      int col = col0 + wn*64 + j*16 + (lane&15);
#pragma unroll
      for (int r=0;r<4;r++)
        Cf[(size_t)(rbase + r)*ldc + col] = acc[i][j][r];
    }
  }
}

// Fused QKV+G1 projection. grid (32, 25): y<8 Q(silu), <16 K->e (exp),
// <24 V, ==24 G1.
__global__ __launch_bounds__(256, 4) void proj_kernel(
    const unsigned short* __restrict__ X,
    const unsigned short* __restrict__ Wq, const unsigned short* __restrict__ Wk,
    const unsigned short* __restrict__ Wv, const unsigned short* __restrict__ Wg1,
    unsigned short* __restrict__ Qb, unsigned short* __restrict__ Eb,
    unsigned short* __restrict__ Vb, unsigned short* __restrict__ G1b)
{
  __shared__ unsigned short sA[128*64], sB[128*64];
  int tid = threadIdx.x;
  int which = blockIdx.y >> 3;
  const unsigned short* Bp = (which==0)?Wq:(which==1)?Wk:(which==2)?Wv:Wg1;
  int row0 = blockIdx.x * 128;
  int col0 = (which==3) ? 0 : (blockIdx.y & 7) * 128;
  f32x4 acc[4][4] = {};
  gemm_core(X, Bp, HIDN, row0, col0, sA, sB, acc, tid);
  if      (which==0) epilogue_lds(acc,row0,col0,tid,HIDN,1,Qb, sA);
  else if (which==1) epilogue_lds(acc,row0,col0,tid,HIDN,2,Eb, sA);  // e=exp(k)
  else if (which==2) epilogue_lds(acc,row0,col0,tid,HIDN,0,Vb, sA);
  else               epilogue_lds(acc,row0,col0,tid,128 ,0,G1b,sA);
}

// Generic A@B^T. Cb nonnull -> bf16 LDS epilogue (act); else fp32 direct.
__global__ __launch_bounds__(256, 4) void gemm_bt(
    const unsigned short* __restrict__ A, const unsigned short* __restrict__ B,
    int K, int ldc, int act, float* __restrict__ Cf,
    unsigned short* __restrict__ Cb)
{
  __shared__ unsigned short sA[128*64], sB[128*64];
  int tid = threadIdx.x;
  int row0 = blockIdx.x * 128, col0 = blockIdx.y * 128;
  f32x4 acc[4][4] = {};
  gemm_core(A, B, K, row0, col0, sA, sB, acc, tid);
  if (Cb) epilogue_lds(acc, row0, col0, tid, ldc, act, Cb, sA);
  else    epilogue_f32(acc, row0, col0, tid, ldc, Cf);
}

// ============ fused attention: pass1 + prefix + pass3 + norm ==============
// Cooperative: 256 blocks x 512 thr, 1 block/CU. grid.sync at cross-block
// dependency points. O never leaves LDS; normalized+gated in place.
__global__ __launch_bounds__(512) void attn_fused(
    const unsigned short* __restrict__ Eb, const unsigned short* __restrict__ Qb,
    const unsigned short* __restrict__ Vb, unsigned short* __restrict__ U,
    float* __restrict__ Esum, float* __restrict__ SumSq,
    const unsigned short* __restrict__ Gt, const unsigned short* __restrict__ gnw,
    unsigned short* __restrict__ Onorm)
{
  cg::grid_group gridg = cg::this_grid();
  __shared__ unsigned short smem[2*128*LDSP];     // ~68 KB
  __shared__ float seg_part[4*128];
  unsigned short* bufA = smem;
  unsigned short* bufB = smem + 128*LDSP;

  int tid = threadIdx.x;
  const int lane = tid & 63, quad = lane >> 4;
  const int w = tid >> 6, wm = w & 3, wn = w >> 2;
  const int Rb = wm*32, Cbnd = wn*64;
  int blk = blockIdx.x;
  int bh = blk >> 4, ch = blk & 15;
  int b = bh >> 3, h = bh & 7;
  size_t rowbase = (size_t)(b*T_SEQ + ch*128)*HIDN + h*128;

  // ========== P1: Esum[k], Ut[v][k] = sum_s V[s][v] e[s][k] ==========
#pragma unroll
  for (int i=0;i<4;i++){                   // transpose-stage V (bufA), e (bufB)
    int u = tid + i*512; int t = u >> 4, kc = (u & 15)*8;
    unsigned short tmp[8];
    *(uint4*)tmp = *(const uint4*)&Vb[rowbase + (size_t)t*HIDN + kc];
#pragma unroll
    for (int j=0;j<8;j++) bufA[(kc+j)*LDSP + t] = tmp[j];
    *(uint4*)tmp = *(const uint4*)&Eb[rowbase + (size_t)t*HIDN + kc];
#pragma unroll
    for (int j=0;j<8;j++) bufB[(kc+j)*LDSP + t] = tmp[j];
  }
  __syncthreads();

  { // Esum[k] = row sums of Et (bufB)
    int seg = tid >> 7, k = tid & 127;
    float s = 0.f;
    for (int c = seg*32; c < seg*32+32; ++c) s += bu2f(bufB[k*LDSP + c]);
    seg_part[seg*128 + k] = s;
  }
  __syncthreads();
  if (tid < 128)
    Esum[(size_t)blk*128 + tid] =
        seg_part[tid] + seg_part[128+tid] + seg_part[256+tid] + seg_part[384+tid];

  { // Ut = Vt @ Et^T
    f32x4 acc[2][4] = {};
    short8 av[2], bv[4];
#pragma unroll
    for (int s0=0; s0<128; s0+=32){
#pragma unroll
      for (int i=0;i<2;i++)
        av[i] = *(const short8*)(bufA + (Rb + i*16 + (lane&15))*LDSP + s0 + quad*8);
#pragma unroll
      for (int j=0;j<4;j++)
        bv[j] = *(const short8*)(bufB + (Cbnd + j*16 + (lane&15))*LDSP + s0 + quad*8);
#pragma unroll
      for (int i=0;i<2;i++)
#pragma unroll
        for (int j=0;j<4;j++)
          acc[i][j] = __builtin_amdgcn_mfma_f32_16x16x32_bf16(av[i], bv[j], acc[i][j], 0,0,0);
    }
    __syncthreads();                       // all bufA/bufB reads done
#pragma unroll
    for (int i=0;i<2;i++)
#pragma unroll
      for (int j=0;j<4;j++){
        int k = Cbnd + j*16 + (lane&15);
#pragma unroll
        for (int r=0;r<4;r++){
          int v = Rb + i*16 + quad*4 + r;
          bufB[v*LDSP + k] = f2bu(acc[i][j][r]);
        }
      }
    __syncthreads();
    unsigned short* Ub = U + (size_t)blk*16384;
#pragma unroll
    for (int i=0;i<4;i++){
      int u = tid + i*512; int v = u >> 4, kc = (u & 15)*8;
      *(uint4*)&Ub[v*128 + kc] = *(const uint4*)&bufB[v*LDSP + kc];
    }
  }
  __threadfence();
  gridg.sync();

  // ========== P2: exclusive prefix over chunks (in place) ==========
  {
    int sl = blk & 15;
    if (tid < 256){
      int p = sl*1024 + tid*4;
      float r0=0.f, r1=0.f, r2=0.f, r3=0.f;
      for (int c=0;c<16;c++){
        ushort4* ptr = (ushort4*)&U[(size_t)(bh*16 + c)*16384 + p];
        ushort4 t = *ptr;
        ushort4 wv;
        wv.x=f2bu(r0); wv.y=f2bu(r1); wv.z=f2bu(r2); wv.w=f2bu(r3);
        *ptr = wv;
        r0 += bu2f(t.x); r1 += bu2f(t.y); r2 += bu2f(t.z); r3 += bu2f(t.w);
      }
    }
    if (sl == 0 && tid < 128){
      float r = 0.f;
      for (int c=0;c<16;c++){
        float* q = &Esum[(size_t)(bh*16 + c)*128 + tid];
        float t = *q; *q = r; r += t;
      }
    }
  }
  __threadfence();
  gridg.sync();

  // ========== P3: O = qn@Cprev + causal(qn@e^T)@V ; SumSq ==========
#pragma unroll
  for (int i=0;i<4;i++){                   // stage Q (bufA), e (bufB) row-major
    int u = tid + i*512; int t = u >> 4, kc = (u & 15)*8;
    *(uint4*)&bufA[t*LDSP + kc] = *(const uint4*)&Qb[rowbase + (size_t)t*HIDN + kc];
    *(uint4*)&bufB[t*LDSP + kc] = *(const uint4*)&Eb[rowbase + (size_t)t*HIDN + kc];
  }
  __syncthreads();

  {  // qn = q*SCALE/E_t ; 4-way segmented inclusive cumsum over t
    int col = tid & 127, seg = tid >> 7;
    float psum = 0.f;
    for (int s = seg*32; s < seg*32+32; ++s) psum += bu2f(bufB[s*LDSP + col]);
    seg_part[seg*128 + col] = psum;
    __syncthreads();
    float run = Esum[(size_t)blk*128 + col];
    for (int ss=0; ss<4; ++ss) if (ss < seg) run += seg_part[ss*128 + col];
    for (int s = seg*32; s < seg*32+32; ++s){
      run += bu2f(bufB[s*LDSP + col]);
      float q = bu2f(bufA[s*LDSP + col]);
      bufA[s*LDSP + col] = f2bu(q * SCALE * __builtin_amdgcn_rcpf(run));
    }
  }
  __syncthreads();

  f32x4 accO[2][4] = {}, accP[2][4] = {};
  {
    const unsigned short* Ublk = U + (size_t)blk*16384;
    short8 av[2], bv[4];
#pragma unroll
    for (int k0=0; k0<128; k0+=32){
#pragma unroll
      for (int i=0;i<2;i++)
        av[i] = *(const short8*)(bufA + (Rb + i*16 + (lane&15))*LDSP + k0 + quad*8);
#pragma unroll
      for (int j=0;j<4;j++)
        bv[j] = *(const short8*)(Ublk + (size_t)(Cbnd + j*16 + (lane&15))*128 + k0 + quad*8);
#pragma unroll
      for (int i=0;i<2;i++)
#pragma unroll
        for (int j=0;j<4;j++)
          accO[i][j] = __builtin_amdgcn_mfma_f32_16x16x32_bf16(av[i], bv[j], accO[i][j], 0,0,0);
#pragma unroll
      for (int j=0;j<4;j++)
        bv[j] = *(const short8*)(bufB + (Cbnd + j*16 + (lane&15))*LDSP + k0 + quad*8);
#pragma unroll
      for (int i=0;i<2;i++)
#pragma unroll
        for (int j=0;j<4;j++)
          accP[i][j] = __builtin_amdgcn_mfma_f32_16x16x32_bf16(av[i], bv[j], accP[i][j], 0,0,0);
    }
  }
  __syncthreads();

  // masked P -> bufA [t][s] ; V^T -> bufB [v][s]
#pragma unroll
  for (int i=0;i<2;i++){
#pragma unroll
    for (int j=0;j<4;j++){
      int s = Cbnd + j*16 + (lane&15);
#pragma unroll
      for (int r=0;r<4;r++){
        int t = Rb + i*16 + quad*4 + r;
        bufA[t*LDSP + s] = f2bu(s <= t ? accP[i][j][r] : 0.f);
      }
    }
  }
#pragma unroll
  for (int i=0;i<4;i++){
    int u = tid + i*512; int t = u >> 4, kc = (u & 15)*8;
    unsigned short tmp[8];
    *(uint4*)tmp = *(const uint4*)&Vb[rowbase + (size_t)t*HIDN + kc];
#pragma unroll
    for (int j=0;j<8;j++) bufB[(kc+j)*LDSP + t] = tmp[j];
  }
  __syncthreads();

  {  // intra: O += P @ Vt^T
    short8 av[2], bv[4];
#pragma unroll
    for (int k0=0; k0<128; k0+=32){
#pragma unroll
      for (int i=0;i<2;i++)
        av[i] = *(const short8*)(bufA + (Rb + i*16 + (lane&15))*LDSP + k0 + quad*8);
#pragma unroll
      for (int j=0;j<4;j++)
        bv[j] = *(const short8*)(bufB + (Cbnd + j*16 + (lane&15))*LDSP + k0 + quad*8);
#pragma unroll
      for (int i=0;i<2;i++)
#pragma unroll
        for (int j=0;j<4;j++)
          accO[i][j] = __builtin_amdgcn_mfma_f32_16x16x32_bf16(av[i], bv[j], accO[i][j], 0,0,0);
    }
  }
  __syncthreads();                        // all bufA (P) reads done

  // O -> bufA (bf16), stays in LDS
#pragma unroll
  for (int i=0;i<2;i++){
#pragma unroll
    for (int j=0;j<4;j++){
      int v = Cbnd + j*16 + (lane&15);
#pragma unroll
      for (int r=0;r<4;r++){
        int t = Rb + i*16 + quad*4 + r;
        bufA[t*LDSP + v] = f2bu(accO[i][j][r]);
      }
    }
  }
  __syncthreads();

  {  // per-row sum of squares (this head's 128 cols) -> atomic SumSq
    int seg = tid >> 7, row = tid & 127;
    float s = 0.f;
    for (int c = seg*32; c < seg*32+32; ++c){
      float x = bu2f(bufA[row*LDSP + c]); s += x*x;
    }
    seg_part[seg*128 + row] = s;
  }
  __syncthreads();
  if (tid < 128){
    float s = seg_part[tid] + seg_part[128+tid] + seg_part[256+tid] + seg_part[384+tid];
    atomicAdd(&SumSq[(size_t)b*T_SEQ + ch*128 + tid], s);
  }
  __threadfence();
  gridg.sync();

  // ========== P4: Onorm = O * rstd * gnw * swish(gate) ==========
#pragma unroll
  for (int i=0;i<4;i++){
    int u = tid + i*512; int t = u >> 4, kc = (u & 15)*8;
    float rstd = rsqrtf(SumSq[(size_t)b*T_SEQ + ch*128 + t] * (1.f/1024.f) + 1e-5f);
    float o[8], g[8], wv[8];
    up8(&bufA[t*LDSP + kc], o);
    up8(&Gt[rowbase + (size_t)t*HIDN + kc], g);
    up8(&gnw[h*128 + kc], wv);
    unsigned short r8[8];
#pragma unroll
    for (int j=0;j<8;j++) r8[j] = f2bu(o[j] * rstd * wv[j] * g[j]);
    *(uint4*)&Onorm[rowbase + (size_t)t*HIDN + kc] = *(const uint4*)r8;
  }
}

// ---------------- launch ----------------
extern "C" void kernel_launch(void* const* d_in, const int* in_sizes, int n_in,
                              void* d_out, int out_size, void* d_ws, size_t ws_size,
                              hipStream_t stream) {
  unsigned short* wsS = (unsigned short*)d_ws;     // ~69 MiB used

  unsigned short* Xc   = wsS;              // 4,194,304
  unsigned short* Wqc  = wsS + 4194304;
  unsigned short* Wkc  = wsS + 5242880;
  unsigned short* Wvc  = wsS + 6291456;
  unsigned short* Woc  = wsS + 7340032;
  unsigned short* Wg1c = wsS + 8388608;
  unsigned short* Wg2c = wsS + 8519680;
  unsigned short* gnwc = wsS + 8650752;
  unsigned short* Qb   = wsS + 8651776;
  unsigned short* Eb   = wsS + 12846080;   // e = exp(k), bf16
  unsigned short* Vb   = wsS + 17040384;
  unsigned short* G1b  = wsS + 21234688;
  unsigned short* Gt   = wsS + 21758976;
  unsigned short* Ub   = wsS + 25953280;
  float*          Esum = (float*)(wsS + 34341888);  // 32,768 floats
  float*          SumSq= (float*)(wsS + 34407424);  //  4,096 floats
  unsigned short* Onorm = Qb;              // Q dead after attn_fused P3

  convert_all<<<8453, 256, 0, stream>>>(
      (const float*)d_in[0], (const float*)d_in[1], (const float*)d_in[2],
      (const float*)d_in[3], (const float*)d_in[4], (const float*)d_in[5],
      (const float*)d_in[6], (const float*)d_in[7], wsS, SumSq);

  proj_kernel<<<dim3(32,25), 256, 0, stream>>>(Xc, Wqc, Wkc, Wvc, Wg1c, Qb, Eb, Vb, G1b);
  gemm_bt   <<<dim3(32,8),  256, 0, stream>>>(G1b, Wg2c, 128, HIDN, 1, nullptr, Gt);

  {
    const unsigned short* aEb = Eb; const unsigned short* aQb = Qb;
    const unsigned short* aVb = Vb; unsigned short* aUb = Ub;
    float* aEsum = Esum; float* aSumSq = SumSq;
    const unsigned short* aGt = Gt; const unsigned short* agnw = gnwc;
    unsigned short* aOn = Onorm;
    void* kargs[] = { (void*)&aEb, (void*)&aQb, (void*)&aVb, (void*)&aUb,
                      (void*)&aEsum, (void*)&aSumSq, (void*)&aGt, (void*)&agnw,
                      (void*)&aOn };
    hipLaunchCooperativeKernel((void*)attn_fused, dim3(256), dim3(512),
                               kargs, 0, stream);
  }

  gemm_bt   <<<dim3(32,8),  256, 0, stream>>>(Onorm, Woc, HIDN, HIDN, 0,
                                              (float*)d_out, nullptr);
}